// Round 1
// baseline (384.467 us; speedup 1.0000x reference)
//
#include <hip/hip_runtime.h>
#include <hip/hip_bf16.h>

// Problem constants (fixed by reference setup_inputs)
constexpr int BS = 64, C = 256, NH = 4, DH = 64, T = 6, D = 192;
constexpr int HW = 3136;
constexpr int NT = 112;                  // chunk size over HW (7 n-tiles of 16)
constexpr int S = 7, CPB = 4;            // HW splits per (b,h), chunks per split
constexpr int PNF = 136;                 // fch/pw row stride (272B: 16B-aligned b128 frags)
constexpr int PNS = 116;                 // st row stride (fp32)
constexpr int QP = 72;                   // qs row stride (144B, 16B-aligned)
constexpr float SCALE = 0.125f;          // dh^-0.5
constexpr float LN_EPS = 1e-5f;

typedef short bf16x8 __attribute__((ext_vector_type(8)));
typedef float f32x4 __attribute__((ext_vector_type(4)));

__device__ inline unsigned short f2bf(float x) {
    union { float f; unsigned u; } v; v.f = x;
    unsigned r = v.u + 0x7FFFu + ((v.u >> 16) & 1u);   // RNE
    return (unsigned short)(r >> 16);
}

// pack 4 floats -> 4 bf16 and store 8B to LDS
__device__ inline void st_bf8(unsigned short* dst, float4 p) {
    unsigned lo = (unsigned)f2bf(p.x) | ((unsigned)f2bf(p.y) << 16);
    unsigned hi = (unsigned)f2bf(p.z) | ((unsigned)f2bf(p.w) << 16);
    *(uint2*)dst = make_uint2(lo, hi);
}

// Workgroup barrier that drains ONLY lgkm (LDS) — keeps global prefetch
// loads in flight across the barrier (unlike __syncthreads, which the
// compiler lowers with a full vmcnt(0) drain).
__device__ inline void wg_barrier_lgkm() {
    asm volatile("s_waitcnt lgkmcnt(0)" ::: "memory");
    __builtin_amdgcn_s_barrier();
    asm volatile("" ::: "memory");
}

// ---------------------------------------------------------------------------
// Kernel 1 (was 2): fused q-projection + attention + mlp via MFMA, split over HW.
// grid = BS*NH*S = 1792; 384 threads = 6 waves.
//   prologue: q[t,c] = tokens[t,b,:] . q_w[c,:]  (one dot per thread, 6x64=384)
//   scores: S[t,n] = Q x F     (A=Q b128 frags, B=F strided-u16 frags)
//   PV+MLP: D[c,t~] = F x [P;W] (A=F b128, B=PW b128; t~0-5=O, 6-11=MLP)
// Features staged per chunk as bf16 [c][n]; K padded 112->128 (zeros).
// Staging is software-pipelined: chunk cc+1's global loads are issued into
// registers right after chunk cc's LDS commit, and stay in flight across the
// lgkm-only barriers while scores/softmax/PV run.
// ---------------------------------------------------------------------------
__global__ __launch_bounds__(384) void fused_attn_mlp(
    const float* __restrict__ feat,     // [BS,C,HW]
    const float* __restrict__ mlp_w,    // [T,HW]
    const float* __restrict__ tokens,   // [T,BS,D]
    const float* __restrict__ q_w,      // [C,D]
    const float* __restrict__ q_b,      // [C]
    float* __restrict__ out_attn,       // [BS,NH,T,HW] (pre-softmax scores)
    float* __restrict__ o_part,         // [BS*NH*S][T][DH]
    float* __restrict__ mlp_part,       // [BS*NH*S][T][DH]
    float* __restrict__ ml_part)        // [BS*NH*S][T][2]
{
    int bh = blockIdx.x / S, sp = blockIdx.x % S;
    int b = bh / NH, h = bh % NH;
    int tid = threadIdx.x;
    int wave = tid >> 6, lane = tid & 63;
    int col = lane & 15, quad = lane >> 4;

    __shared__ unsigned short fch[DH][PNF];   // 17.4 KB bf16 features chunk
    __shared__ unsigned short pw[16][PNF];    // 4.4 KB  rows 0-5 = P, 6-11 = W, 12-15 = 0
    __shared__ unsigned short qs[16][QP];     // 2.3 KB  bf16 Q (rows 6-15 garbage; discarded)
    __shared__ float st[T][PNS];              // 2.8 KB  fp32 scores chunk
    __shared__ float m_s[T], l_s[T], al_s[T];

    const float* fbase = feat + ((size_t)b * C + h * DH) * HW;
    float* obase = out_attn + ((size_t)bh * T) * HW;

    // ---- q projection: thread (wave=t, lane=c2), L2-hot loads issued FIRST
    // so the qs store's vmcnt wait does not cover the chunk-0 prefetch below.
    float qacc;
    {
        const float4* tr = (const float4*)&tokens[((size_t)wave * BS + b) * D];
        const float4* qr = (const float4*)&q_w[(size_t)(h * DH + lane) * D];
        float acc = 0.f;
#pragma unroll 4
        for (int v = 0; v < D / 4; ++v) {
            float4 t4 = tr[v], w4 = qr[v];
            acc += t4.x * w4.x + t4.y * w4.y + t4.z * w4.z + t4.w * w4.w;
        }
        qacc = acc + q_b[h * DH + lane];
    }

    // ---- issue chunk-0 prefetch (features + mlp_w) into registers
    float4 pf0, pf1, pf2, pf3, pf4, pm;
    {
        const int n0 = sp * CPB * NT;
        pf0 = *(const float4*)&fbase[(size_t)(tid / 28) * HW + n0 + 4 * (tid % 28)];
        pf1 = *(const float4*)&fbase[(size_t)((tid + 384) / 28) * HW + n0 + 4 * ((tid + 384) % 28)];
        pf2 = *(const float4*)&fbase[(size_t)((tid + 768) / 28) * HW + n0 + 4 * ((tid + 768) % 28)];
        pf3 = *(const float4*)&fbase[(size_t)((tid + 1152) / 28) * HW + n0 + 4 * ((tid + 1152) % 28)];
        if (tid < 256)
            pf4 = *(const float4*)&fbase[(size_t)((tid + 1536) / 28) * HW + n0 + 4 * ((tid + 1536) % 28)];
        if (tid < 168)
            pm = *(const float4*)&mlp_w[(size_t)(tid / 28) * HW + n0 + 4 * (tid % 28)];
    }

    // ---- one-time zero of pads (staging never touches these)
    for (int i = tid; i < 16 * PNF; i += 384) pw[i / PNF][i % PNF] = 0;
    for (int i = tid; i < DH * 16; i += 384) fch[i / 16][112 + (i % 16)] = 0;
    if (tid < T) { m_s[tid] = -3e38f; l_s[tid] = 0.f; }
    qs[wave][lane] = f2bf(qacc);

    f32x4 accPW = {0.f, 0.f, 0.f, 0.f};    // waves 0-3: [c-tile=wave][t~=col]
    wg_barrier_lgkm();

#pragma unroll 1
    for (int cc = 0; cc < CPB; ++cc) {
        const int n0 = (sp * CPB + cc) * NT;

        // ---- commit prefetched chunk to LDS as bf16 (waits vmcnt by dependency)
        st_bf8(&fch[tid / 28][4 * (tid % 28)], pf0);
        st_bf8(&fch[(tid + 384) / 28][4 * ((tid + 384) % 28)], pf1);
        st_bf8(&fch[(tid + 768) / 28][4 * ((tid + 768) % 28)], pf2);
        st_bf8(&fch[(tid + 1152) / 28][4 * ((tid + 1152) % 28)], pf3);
        if (tid < 256)
            st_bf8(&fch[(tid + 1536) / 28][4 * ((tid + 1536) % 28)], pf4);
        if (tid < 168)
            st_bf8(&pw[6 + tid / 28][4 * (tid % 28)], pm);

        // ---- issue next chunk's prefetch; stays in flight across barriers
        if (cc + 1 < CPB) {
            const int n1 = n0 + NT;
            pf0 = *(const float4*)&fbase[(size_t)(tid / 28) * HW + n1 + 4 * (tid % 28)];
            pf1 = *(const float4*)&fbase[(size_t)((tid + 384) / 28) * HW + n1 + 4 * ((tid + 384) % 28)];
            pf2 = *(const float4*)&fbase[(size_t)((tid + 768) / 28) * HW + n1 + 4 * ((tid + 768) % 28)];
            pf3 = *(const float4*)&fbase[(size_t)((tid + 1152) / 28) * HW + n1 + 4 * ((tid + 1152) % 28)];
            if (tid < 256)
                pf4 = *(const float4*)&fbase[(size_t)((tid + 1536) / 28) * HW + n1 + 4 * ((tid + 1536) % 28)];
            if (tid < 168)
                pm = *(const float4*)&mlp_w[(size_t)(tid / 28) * HW + n1 + 4 * (tid % 28)];
        }
        wg_barrier_lgkm();

        // ---- scores MFMA: n-tile(s) per wave
        for (int tile = wave; tile < 7; tile += 6) {
            bf16x8 a0 = *(const bf16x8*)&qs[col][quad * 8];
            bf16x8 a1 = *(const bf16x8*)&qs[col][32 + quad * 8];
            bf16x8 b0, b1;
#pragma unroll
            for (int j = 0; j < 8; ++j) {
                b0[j] = (short)fch[quad * 8 + j][tile * 16 + col];
                b1[j] = (short)fch[32 + quad * 8 + j][tile * 16 + col];
            }
            f32x4 acc = {0.f, 0.f, 0.f, 0.f};
            acc = __builtin_amdgcn_mfma_f32_16x16x32_bf16(a0, b0, acc, 0, 0, 0);
            acc = __builtin_amdgcn_mfma_f32_16x16x32_bf16(a1, b1, acc, 0, 0, 0);
#pragma unroll
            for (int reg = 0; reg < 4; ++reg) {
                int r = quad * 4 + reg;
                if (r < 6) st[r][tile * 16 + col] = acc[reg] * SCALE;
            }
        }
        wg_barrier_lgkm();

        // ---- online softmax (wave t) + coalesced score write-out
        {
            int t = wave;
            float v0 = st[t][lane];
            float v1 = (lane + 64 < NT) ? st[t][lane + 64] : -3e38f;
            float mloc = fmaxf(v0, v1);
#pragma unroll
            for (int off = 32; off; off >>= 1) mloc = fmaxf(mloc, __shfl_down(mloc, off));
            mloc = __shfl(mloc, 0);
            float m_old = m_s[t], m_new = fmaxf(m_old, mloc);
            float p0 = __expf(v0 - m_new);
            float p1 = (lane + 64 < NT) ? __expf(v1 - m_new) : 0.f;
            pw[t][lane] = f2bf(p0);
            if (lane + 64 < NT) pw[t][lane + 64] = f2bf(p1);
            float ssum = p0 + p1;
#pragma unroll
            for (int off = 32; off; off >>= 1) ssum += __shfl_down(ssum, off);
            if (lane == 0) {
                float alpha = __expf(m_old - m_new);
                l_s[t] = l_s[t] * alpha + ssum;
                m_s[t] = m_new;
                al_s[t] = alpha;
            }
            if (lane < NT / 4) {   // coalesced float4 out_attn write
                *(float4*)&obase[(size_t)t * HW + n0 + 4 * lane] =
                    *(const float4*)&st[t][4 * lane];
            }
        }
        wg_barrier_lgkm();

        // ---- PV + MLP MFMA: wave = c-tile (waves 0-3)
        if (wave < 4) {
            float alpha = (col < 6) ? al_s[col] : 1.0f;
            accPW *= alpha;
#pragma unroll
            for (int ks = 0; ks < 4; ++ks) {
                bf16x8 af = *(const bf16x8*)&fch[wave * 16 + col][ks * 32 + quad * 8];
                bf16x8 bf = *(const bf16x8*)&pw[col][ks * 32 + quad * 8];
                accPW = __builtin_amdgcn_mfma_f32_16x16x32_bf16(af, bf, accPW, 0, 0, 0);
            }
        }
        wg_barrier_lgkm();   // fch/pw/st reused next chunk
    }

    // ---- epilogue: scatter D tiles to partials
    if (wave < 4) {
#pragma unroll
        for (int reg = 0; reg < 4; ++reg) {
            int c2 = wave * 16 + quad * 4 + reg;   // row = channel
            if (col < 6) {
                o_part[((size_t)blockIdx.x * T + col) * DH + c2] = accPW[reg];
            } else if (col < 12) {
                mlp_part[((size_t)blockIdx.x * T + (col - 6)) * DH + c2] = accPW[reg];
            }
        }
    }
    if (tid < 2 * T) {
        int t = tid >> 1;
        ml_part[((size_t)blockIdx.x * T + t) * 2 + (tid & 1)] =
            (tid & 1) ? l_s[t] : m_s[t];
    }
}

// ---------------------------------------------------------------------------
// Kernel 2: alpha-gate + merge split partials + proj + residual + LayerNorm.
// alpha is computed in-place (one 192-MAC dot per thread) against the tokens
// row this block already needs for the residual — kills the old qalpha kernel.
// ---------------------------------------------------------------------------
__global__ __launch_bounds__(256) void merge_proj_ln_kernel(
    const float* __restrict__ o_part,
    const float* __restrict__ mlp_part,
    const float* __restrict__ ml_part,
    const float* __restrict__ mlp_b,    // [T]
    const float* __restrict__ alpha_w,  // [C,D]
    const float* __restrict__ alpha_b,  // [C]
    const float* __restrict__ tokens,   // [T,BS,D]
    const float* __restrict__ proj_w,   // [D,C]
    const float* __restrict__ proj_b,   // [D]
    const float* __restrict__ ln_g,     // [D]
    const float* __restrict__ ln_b,     // [D]
    float* __restrict__ out_tok)        // [T,BS,D]
{
    int tb = blockIdx.x;
    int t = tb / BS, b = tb % BS;
    int tid = threadIdx.x;
    __shared__ float tok_s[D];
    __shared__ float g_s[C];
    __shared__ float r1[4], r2[4];

    if (tid < D / 4)
        *(float4*)&tok_s[4 * tid] = *(const float4*)&tokens[(size_t)tb * D + 4 * tid];
    __syncthreads();

    {
        int c = tid;
        // gate = h_sigmoid(tokens . alpha_w[c] + alpha_b[c]) * 2
        const float4* ar = (const float4*)(alpha_w + (size_t)c * D);
        float acca = 0.f;
#pragma unroll 8
        for (int v = 0; v < D / 4; ++v) {
            float4 w4 = ar[v];
            float4 t4 = *(const float4*)&tok_s[4 * v];
            acca += w4.x * t4.x + w4.y * t4.y + w4.z * t4.z + w4.w * t4.w;
        }
        float aa = acca + alpha_b[c] + 3.0f;
        float gate = fminf(fmaxf(aa, 0.0f), 6.0f) * (2.0f / 6.0f);

        int h = c >> 6, cl = c & 63;
        int bh = b * NH + h;
        float m[S], l[S];
        float M = -3e38f;
#pragma unroll
        for (int s = 0; s < S; ++s) {
            size_t blk = (size_t)(bh * S + s);
            m[s] = ml_part[(blk * T + t) * 2 + 0];
            l[s] = ml_part[(blk * T + t) * 2 + 1];
            M = fmaxf(M, m[s]);
        }
        float L = 0.f, O = 0.f, MLP = 0.f;
#pragma unroll
        for (int s = 0; s < S; ++s) {
            float w = __expf(m[s] - M);
            size_t blk = (size_t)(bh * S + s);
            size_t pidx = (blk * T + t) * DH + cl;
            L += l[s] * w;
            O += o_part[pidx] * w;
            MLP += mlp_part[pidx];
        }
        g_s[c] = (MLP + mlp_b[t] + O / L) * gate;
    }
    __syncthreads();

    if (tid < D) {
        int d = tid;
        float acc = proj_b[d] + tok_s[d];
        const float4* pr = (const float4*)(proj_w + (size_t)d * C);
#pragma unroll 8
        for (int v = 0; v < C / 4; ++v) {
            float4 w4 = pr[v];
            float4 g4 = *(const float4*)&g_s[4 * v];
            acc += w4.x * g4.x + w4.y * g4.y + w4.z * g4.z + w4.w * g4.w;
        }

        float s1 = acc, s2 = acc * acc;
#pragma unroll
        for (int off = 32; off; off >>= 1) { s1 += __shfl_down(s1, off); s2 += __shfl_down(s2, off); }
        int wv = d >> 6, lane = d & 63;
        if (lane == 0) { r1[wv] = s1; r2[wv] = s2; }
        __syncthreads();
        float sum1 = r1[0] + r1[1] + r1[2];
        float sum2 = r2[0] + r2[1] + r2[2];
        float mu = sum1 * (1.0f / D);
        float var = sum2 * (1.0f / D) - mu * mu;
        float inv = rsqrtf(var + LN_EPS);
        out_tok[(size_t)tb * D + d] = (acc - mu) * inv * ln_g[d] + ln_b[d];
    } else {
        __syncthreads();
    }
}

// ---------------------------------------------------------------------------
extern "C" void kernel_launch(void* const* d_in, const int* in_sizes, int n_in,
                              void* d_out, int out_size, void* d_ws, size_t ws_size,
                              hipStream_t stream) {
    const float* features = (const float*)d_in[0];
    const float* tokens   = (const float*)d_in[1];
    const float* mlp_w    = (const float*)d_in[2];
    const float* mlp_b    = (const float*)d_in[3];
    const float* q_w      = (const float*)d_in[4];
    const float* q_b      = (const float*)d_in[5];
    const float* alpha_w  = (const float*)d_in[6];
    const float* alpha_b  = (const float*)d_in[7];
    const float* proj_w   = (const float*)d_in[8];
    const float* proj_b   = (const float*)d_in[9];
    const float* ln_g     = (const float*)d_in[10];
    const float* ln_b     = (const float*)d_in[11];

    float* out_tok  = (float*)d_out;                   // [T,BS,D]
    float* out_attn = (float*)d_out + T * BS * D;      // [BS,NH,T,HW]

    constexpr int NBLK = BS * NH * S;                  // 1792
    float* ml_part  = (float*)d_ws;                    // NBLK*T*2
    float* o_part   = ml_part + NBLK * T * 2;          // NBLK*T*DH
    float* mlp_part = o_part + NBLK * T * DH;          // NBLK*T*DH

    fused_attn_mlp<<<NBLK, 384, 0, stream>>>(
        features, mlp_w, tokens, q_w, q_b, out_attn, o_part, mlp_part, ml_part);

    merge_proj_ln_kernel<<<T * BS, 256, 0, stream>>>(
        o_part, mlp_part, ml_part, mlp_b, alpha_w, alpha_b, tokens,
        proj_w, proj_b, ln_g, ln_b, out_tok);
}